// Round 4
// baseline (10794.349 us; speedup 1.0000x reference)
//
#include <hip/hip_runtime.h>
#include <hip/hip_bf16.h>

// LSTM stack B=32, T=512, H=1024, L=2.  Round 4: round-3 structure with the
// h-publish race fixed (shfl-pack, no LDS intermediary, no extra sync).
//   128 persistent wgs x 512 threads. tids 0-255 = layer-0 slice (8 h-cols),
//   tids 256-511 = layer-1 slice (8 h-cols), software-pipelined one step apart.
//   Grid sync: one flag/wg (SYSTEM scope), wave 0 of every wg polls all 128
//   flags directly (2 dword loads/lane, hot spin).
//   h exchange: relaxed AGENT 8B atomics; publish via intra-row shfl pack.

typedef __attribute__((ext_vector_type(8))) short short8;
typedef __attribute__((ext_vector_type(4))) float f32x4;

__device__ __forceinline__ unsigned short f2bu(float f) {
    __hip_bfloat16 h = __float2bfloat16(f);
    return *(unsigned short*)&h;
}
__device__ __forceinline__ float b2f(unsigned short u) {
    __hip_bfloat16 h = *(__hip_bfloat16*)&u;
    return __bfloat162float(h);
}

union U16 { unsigned long long u[2]; short8 s; };

__device__ __forceinline__ short8 ald16(const unsigned short* p) {
    U16 x;
    x.u[0] = __hip_atomic_load((unsigned long long*)p,       __ATOMIC_RELAXED, __HIP_MEMORY_SCOPE_AGENT);
    x.u[1] = __hip_atomic_load((unsigned long long*)(p + 4), __ATOMIC_RELAXED, __HIP_MEMORY_SCOPE_AGENT);
    return x.s;
}
__device__ __forceinline__ void ast8(unsigned short* p, unsigned long long v) {
    __hip_atomic_store((unsigned long long*)p, v, __ATOMIC_RELAXED, __HIP_MEMORY_SCOPE_AGENT);
}
__device__ __forceinline__ f32x4 mfma16(short8 a, short8 b, f32x4 c) {
    return __builtin_amdgcn_mfma_f32_16x16x32_bf16(a, b, c, 0, 0, 0);
}

// ---------------------------------------------------------------- pack_x
__global__ __launch_bounds__(256) void pack_x(const float* __restrict__ x,
                                              unsigned short* __restrict__ xb) {
    int i = blockIdx.x * 256 + threadIdx.x;
    float4 v = ((const float4*)x)[i];
    ushort4 o;
    o.x = f2bu(v.x); o.y = f2bu(v.y); o.z = f2bu(v.z); o.w = f2bu(v.w);
    ((ushort4*)xb)[i] = o;
}

// ---------------------------------------------------------------- pack_w
// p = w*32 + gate*8 + c   <->  orig col = gate*1024 + w*8 + c
__global__ __launch_bounds__(256) void pack_w(const float* __restrict__ Wx,
                                              const float* __restrict__ Wh,
                                              unsigned short* __restrict__ Wxp,
                                              unsigned short* __restrict__ Whp0,
                                              unsigned short* __restrict__ Wcat) {
    __shared__ float tile[32][257];
    int mi = blockIdx.x >> 9;          // 0:Wx0 1:Wx1 2:Wh0 3:Wh1
    int rem = blockIdx.x & 511;
    int kb = rem >> 4;
    int cb = rem & 15;
    const float* src = (mi == 0) ? Wx : (mi == 1) ? (Wx + 4194304)
                     : (mi == 2) ? Wh : (Wh + 4194304);
    int tid = threadIdx.x;
    for (int pphase = 0; pphase < 8; ++pphase) {
        int row = pphase * 4 + (tid >> 6);
        int col4 = (tid & 63) * 4;
        float4 v = *(const float4*)(src + (size_t)(kb * 32 + row) * 4096 + cb * 256 + col4);
        tile[row][col4 + 0] = v.x; tile[row][col4 + 1] = v.y;
        tile[row][col4 + 2] = v.z; tile[row][col4 + 3] = v.w;
    }
    __syncthreads();
    int j = tid;
    int oc = cb * 256 + j;
    int gate = oc >> 10, hc = oc & 1023, w = hc >> 3, c = hc & 7;
    int p = w * 32 + gate * 8 + c;
    unsigned short* dst;
    if (mi == 0)      dst = Wxp  + (size_t)p * 1024 + kb * 32;
    else if (mi == 2) dst = Whp0 + (size_t)p * 1024 + kb * 32;
    else if (mi == 1) dst = Wcat + (size_t)p * 2048 + kb * 32;
    else              dst = Wcat + (size_t)p * 2048 + 1024 + kb * 32;
    for (int k = 0; k < 32; ++k) dst[k] = f2bu(tile[k][j]);
}

// ---------------------------------------------------------------- pack_misc
__global__ __launch_bounds__(256) void pack_misc(const float* __restrict__ b,
                                                 float* __restrict__ biasp,
                                                 unsigned* __restrict__ bars,
                                                 unsigned* __restrict__ hz) {
    int i = blockIdx.x * 256 + threadIdx.x;   // grid 256 -> 65536
    if (i < 4096) {
        int w = i >> 5, q = i & 31, gate = q >> 3, c = q & 7;
        biasp[i] = b[gate * 1024 + w * 8 + c];
    }
    if (i < 1024) bars[i] = 0u;
    hz[i] = 0u;   // 256KB: both h exchange buffers
}

// ---------------------------------------------------------------- gemm_zx
// C[r][p] = sum_k A[r][k]*Bt[p][k] + biasp[p]; A rows r = b*512+t.
// Output packed: Zx[((p>>5)*512 + t)*32 + b][32] + (p&31)
__global__ __launch_bounds__(256) void gemm_zx(const unsigned short* __restrict__ A,
                                               const unsigned short* __restrict__ Bt,
                                               const float* __restrict__ biasp,
                                               unsigned short* __restrict__ Zx) {
    __shared__ unsigned short Ash[128 * 72];
    __shared__ unsigned short Bsh[128 * 72];
    int tid = threadIdx.x;
    int bn = blockIdx.x & 31, bm = blockIdx.x >> 5;
    int L = tid & 63, wv = tid >> 6;
    int wm = (wv >> 1) * 64, wn = (wv & 1) * 64;
    f32x4 acc[4][4];
    for (int mi = 0; mi < 4; ++mi)
        for (int ni = 0; ni < 4; ++ni)
            acc[mi][ni] = (f32x4){0.f, 0.f, 0.f, 0.f};
    const int rs = tid >> 3;
    const int ch = tid & 7;
    for (int kt = 0; kt < 16; ++kt) {
        int k0 = kt * 64;
        __syncthreads();
#pragma unroll
        for (int it = 0; it < 4; ++it) {
            int r = it * 32 + rs;
            short8 av = *(const short8*)(A + (size_t)(bm * 128 + r) * 1024 + k0 + ch * 8);
            short8 bv = *(const short8*)(Bt + (size_t)(bn * 128 + r) * 1024 + k0 + ch * 8);
            *(short8*)(Ash + r * 72 + ch * 8) = av;
            *(short8*)(Bsh + r * 72 + ch * 8) = bv;
        }
        __syncthreads();
#pragma unroll
        for (int ks = 0; ks < 2; ++ks) {
            int ko = ks * 32 + (L >> 4) * 8;
            short8 af[4], bfv[4];
#pragma unroll
            for (int i = 0; i < 4; ++i)
                af[i] = *(const short8*)(Ash + (wm + i * 16 + (L & 15)) * 72 + ko);
#pragma unroll
            for (int i = 0; i < 4; ++i)
                bfv[i] = *(const short8*)(Bsh + (wn + i * 16 + (L & 15)) * 72 + ko);
#pragma unroll
            for (int mi = 0; mi < 4; ++mi)
#pragma unroll
                for (int ni = 0; ni < 4; ++ni)
                    acc[mi][ni] = mfma16(af[mi], bfv[ni], acc[mi][ni]);
        }
    }
#pragma unroll
    for (int mi = 0; mi < 4; ++mi) {
        int gr0 = bm * 128 + wm + mi * 16 + (L >> 4) * 4;
#pragma unroll
        for (int i = 0; i < 4; ++i) {
            int gr = gr0 + i;
            int bnat = gr >> 9, t = gr & 511;
#pragma unroll
            for (int ni = 0; ni < 4; ++ni) {
                int p = bn * 128 + wn + ni * 16 + (L & 15);
                float v = acc[mi][ni][i] + biasp[p];
                size_t addr = (((size_t)(p >> 5) * 512 + t) * 32 + bnat) * 32 + (p & 31);
                Zx[addr] = f2bu(v);
            }
        }
    }
}

// ---------------------------------------------------------------- step MFMA
template<int LAY>
__device__ __forceinline__ void step_mfma(const unsigned short* __restrict__ h0p,
                                          const unsigned short* __restrict__ h1p,
                                          const short8 (&bfr)[2][16],
                                          int wv, int quad, int m_r,
                                          f32x4 (&acc)[2][2]) {
    constexpr int NK = LAY ? 16 : 8;
    constexpr int KW = LAY ? 512 : 256;
    const unsigned short* ap = (LAY && wv >= 2) ? h1p : h0p;
    int kbase = (LAY && wv >= 2) ? (wv * KW - 1024) : (wv * KW);
#pragma unroll
    for (int ks = 0; ks < NK; ++ks) {
        int ko = kbase + ks * 32 + quad * 8;
        short8 a0 = ald16(ap + m_r * 1024 + ko);
        short8 a1 = ald16(ap + (16 + m_r) * 1024 + ko);
        acc[0][0] = mfma16(a0, bfr[0][ks], acc[0][0]);
        acc[0][1] = mfma16(a0, bfr[1][ks], acc[0][1]);
        acc[1][0] = mfma16(a1, bfr[0][ks], acc[1][0]);
        acc[1][1] = mfma16(a1, bfr[1][ks], acc[1][1]);
    }
}

// ---------------------------------------------------------------- lstm_fused
// 128 wgs x 512 threads; tids<256: layer 0 (w=wgid), tids>=256: layer 1.
__global__ __launch_bounds__(512, 2) void lstm_fused(
        const unsigned short* __restrict__ Whp0,   // [4096][1024]
        const unsigned short* __restrict__ Wcat,   // [4096][2048]
        const unsigned short* __restrict__ Zx,     // [128][512][32][32]
        const float* __restrict__ bias,            // original b [2][4096]
        unsigned short* __restrict__ h0buf,        // [2][32][1024]
        unsigned short* __restrict__ h1buf,        // [2][32][1024]
        unsigned* __restrict__ flags,              // [128]
        float* __restrict__ out) {
    __shared__ float zs[2][4][32][32];             // [half][wave][b][gatecol]
    __shared__ unsigned long long zx8[256];        // L0's 32x32 bf16 Zx block
    unsigned short* zxloc = (unsigned short*)zx8;

    int tid = threadIdx.x, w = blockIdx.x;
    int half = tid >> 8;                 // 0 = layer0, 1 = layer1
    int stid = tid & 255;
    int wv = stid >> 6;                  // sub-wave 0..3
    int L = tid & 63;
    int m_r = L & 15, quad = L >> 4;
    int nk = half ? 16 : 8;
    int K  = half ? 2048 : 1024;

    // hoist B fragments (plain cached loads, once)
    short8 bfr[2][16];
    {
        const unsigned short* wb = half ? (Wcat + (size_t)w * 32 * 2048)
                                        : (Whp0 + (size_t)w * 32 * 1024);
        for (int nt = 0; nt < 2; ++nt)
            for (int ks = 0; ks < nk; ++ks) {
                int n = nt * 16 + m_r;
                int k = wv * (K / 4) + ks * 32 + quad * 8;
                bfr[nt][ks] = *(const short8*)(wb + (size_t)n * K + k);
            }
    }
    int gb = stid >> 3, gc = stid & 7;
    float bi0 = 0.f, bf0 = 0.f, bg0 = 0.f, bo0 = 0.f;
    if (half) {
        bi0 = bias[4096 + 0 * 1024 + w * 8 + gc];
        bf0 = bias[4096 + 1 * 1024 + w * 8 + gc];
        bg0 = bias[4096 + 2 * 1024 + w * 8 + gc];
        bo0 = bias[4096 + 3 * 1024 + w * 8 + gc];
    }
    float creg = 0.f;

    // prefetch Zx block for t=0
    unsigned long long zreg = 0ull;
    if (!half) zreg = ((const unsigned long long*)(Zx + (size_t)w * 512 * 1024))[stid];

    for (int s = 0; s < 513; ++s) {
        int t = half ? s - 1 : s;
        bool active = half ? (s >= 1) : (s < 512);
        if (active) {
            const unsigned short* h0p = h0buf + ((s + 1) & 1) * 32768;
            const unsigned short* h1p = h1buf + ((s + 1) & 1) * 32768;
            if (!half) zx8[stid] = zreg;     // LDS-publish this step's Zx
            f32x4 acc[2][2];
            for (int a = 0; a < 2; ++a)
                for (int bq = 0; bq < 2; ++bq)
                    acc[a][bq] = (f32x4){0.f, 0.f, 0.f, 0.f};
            if (half) step_mfma<1>(h0p, h1p, bfr, wv, quad, m_r, acc);
            else      step_mfma<0>(h0p, h1p, bfr, wv, quad, m_r, acc);
            // prefetch next step's Zx (independent of barrier)
            if (!half && t + 1 < 512)
                zreg = ((const unsigned long long*)(Zx + ((size_t)w * 512 + t + 1) * 1024))[stid];
#pragma unroll
            for (int mt = 0; mt < 2; ++mt)
#pragma unroll
                for (int nt = 0; nt < 2; ++nt)
#pragma unroll
                    for (int i = 0; i < 4; ++i)
                        zs[half][wv][mt * 16 + quad * 4 + i][nt * 16 + m_r] = acc[mt][nt][i];
        }
        __syncthreads();
        if (active) {
            float zi = bi0, zf = bf0, zg = bg0, zo = bo0;
#pragma unroll
            for (int v = 0; v < 4; ++v) {
                zi += zs[half][v][gb][gc];      zf += zs[half][v][gb][8 + gc];
                zg += zs[half][v][gb][16 + gc]; zo += zs[half][v][gb][24 + gc];
            }
            if (!half) {
                zi += b2f(zxloc[gb * 32 + gc]);      zf += b2f(zxloc[gb * 32 + 8 + gc]);
                zg += b2f(zxloc[gb * 32 + 16 + gc]); zo += b2f(zxloc[gb * 32 + 24 + gc]);
            }
            float si = 1.f / (1.f + __expf(-zi));
            float sf = 1.f / (1.f + __expf(-zf));
            float so = 1.f / (1.f + __expf(-zo));
            float cn = sf * creg + si * tanhf(zg);
            creg = cn;
            float h = so * tanhf(cn);
            // ---- h publish via intra-row shfl pack (row = 8 contiguous lanes):
            // lane gc gathers gc+1 (16b) and the pair from gc+2 -> 8B at gc%4==0
            unsigned hv = (unsigned)f2bu(h);
            unsigned lo = hv | (__shfl_down(hv, 1) << 16);
            unsigned hi = __shfl_down(lo, 2);
            if ((gc & 3) == 0) {
                unsigned long long q = (unsigned long long)lo | ((unsigned long long)hi << 32);
                unsigned short* dst = (half ? h1buf : h0buf) + (s & 1) * 32768
                                      + gb * 1024 + w * 8 + gc;
                ast8(dst, q);
            }
            if (half) {
                out[((size_t)gb * 512 + t) * 1024 + w * 8 + gc] = h;
                if (t == 511) {
                    out[16777216 + 32768 + gb * 1024 + w * 8 + gc] = h;
                    out[16777216 + 65536 + 32768 + gb * 1024 + w * 8 + gc] = cn;
                }
            } else if (t == 511) {
                out[16777216 + gb * 1024 + w * 8 + gc] = h;
                out[16777216 + 65536 + gb * 1024 + w * 8 + gc] = cn;
            }
        }
        // ---- flat grid barrier: 1 flag/wg, wave0 polls all 128, hot spin ----
        __syncthreads();   // drains every wave's stores (h, y) before flag
        unsigned tgt = (unsigned)s + 1u;
        if (tid == 0)
            __hip_atomic_store(flags + w, tgt, __ATOMIC_RELAXED, __HIP_MEMORY_SCOPE_SYSTEM);
        if (tid < 64) {
            for (;;) {
                unsigned f0 = __hip_atomic_load(flags + L,      __ATOMIC_RELAXED, __HIP_MEMORY_SCOPE_SYSTEM);
                unsigned f1 = __hip_atomic_load(flags + 64 + L, __ATOMIC_RELAXED, __HIP_MEMORY_SCOPE_SYSTEM);
                if (__all((f0 >= tgt) && (f1 >= tgt))) break;
            }
        }
        __syncthreads();
    }
}

// ---------------------------------------------------------------- launch
extern "C" void kernel_launch(void* const* d_in, const int* in_sizes, int n_in,
                              void* d_out, int out_size, void* d_ws, size_t ws_size,
                              hipStream_t stream) {
    const float* x  = (const float*)d_in[0];
    const float* Wx = (const float*)d_in[1];
    const float* Wh = (const float*)d_in[2];
    const float* bb = (const float*)d_in[3];

    char* ws = (char*)d_ws;
    unsigned short* Wxp  = (unsigned short*)ws;                       //  8MB [4096][1024]
    unsigned short* Whp0 = (unsigned short*)(ws + (8ull  << 20));     //  8MB [4096][1024]
    unsigned short* Wcat = (unsigned short*)(ws + (16ull << 20));     // 16MB [4096][2048]
    unsigned short* xb   = (unsigned short*)(ws + (32ull << 20));     // 32MB
    unsigned short* Zx   = (unsigned short*)(ws + (64ull << 20));     // 128MB
    char* misc           = ws + (192ull << 20);
    float* biasp         = (float*)misc;                              // 16KB
    unsigned* bars       = (unsigned*)(misc + (64 << 10));            // 4KB
    unsigned short* h0b  = (unsigned short*)(misc + (128 << 10));     // 128KB [2][32][1024]
    unsigned short* h1b  = (unsigned short*)(misc + (256 << 10));     // 128KB
    unsigned* hz         = (unsigned*)(misc + (128 << 10));           // both hbufs, 256KB

    float* out = (float*)d_out;

    pack_x<<<16384, 256, 0, stream>>>(x, xb);
    pack_w<<<2048, 256, 0, stream>>>(Wx, Wh, Wxp, Whp0, Wcat);
    pack_misc<<<256, 256, 0, stream>>>(bb, biasp, bars, hz);

    gemm_zx<<<4096, 256, 0, stream>>>(xb, Wxp, biasp, Zx);
    lstm_fused<<<128, 512, 0, stream>>>(Whp0, Wcat, Zx, bb, h0b, h1b, bars, out);
}